// Round 14
// baseline (61.902 us; speedup 1.0000x reference)
//
#include <hip/hip_runtime.h>
#include <math.h>

#define NB 2
#define NN 192
#define DIMX 256
#define HID 1024
#define NROWS (NB * NN)            // 384
#define SCALING 0.17677669529663687f  // 1/sqrt(32)
#define LOG2E 1.4426950408889634f
#define EPS 1e-5f

// workspace layout (float/uint offsets)
#define OFF_KK    0                               // fp32 k-part, NROWS*256
#define OFF_QVP   (OFF_KK + NROWS * DIMX)         // packed (q*s*log2e, v) bf16
#define OFF_TSORT (OFF_QVP + NROWS * DIMX)        // 1024
#define OFF_IDX   (OFF_TSORT + HID)               // 1024 ints
#define OFF_SCP   (OFF_IDX + HID)                 // packed (S,C) uints (HID+1)*256
#define OFF_ATT   (OFF_SCP + (HID + 1) * DIMX)
#define OFF_WB    (OFF_ATT + NROWS * DIMX)        // packed fp16 k-pair weights
// fp16 weight regions in uints (2 k's per uint, per column):
#define WB_QKVH 0       // 98304  : [kp<128][col<768]
#define WB_WO   98304   // 32768  : [kp<128][c<256]
#define WB_WF1  131072  // 131072 : [kp<128][h<1024]
#define WB_WF2  262144  // 131072 : [kp<512][c<256]
#define WB_TOT  393216

typedef __fp16 half2_t __attribute__((ext_vector_type(2)));

__device__ inline unsigned int f2b(float f) {
  const unsigned int u = __float_as_uint(f);
  return (u + 0x7fffu + ((u >> 16) & 1u)) >> 16;
}
__device__ inline float blo(unsigned int u) {
  return __uint_as_float(u << 16);
}
__device__ inline float bhi(unsigned int u) {
  return __uint_as_float(u & 0xffff0000u);
}
__device__ inline unsigned int pkh(float a, float b) {
  union { half2_t h; unsigned int u; } x;
  x.h = __builtin_amdgcn_cvt_pkrtz(a, b);
  return x.u;
}
__device__ inline unsigned int pkh_rn(float a, float b) {
  union { half2_t h; unsigned int u; } x;
  x.h = half2_t{(__fp16)a, (__fp16)b};
  return x.u;
}
__device__ inline float fdot2u(unsigned int wu, unsigned int au, float c) {
  union { unsigned int u; half2_t h; } w, a;
  w.u = wu;
  a.u = au;
  return __builtin_amdgcn_fdot2(a.h, w.h, c, false);
}

// ---- K1: sortrank (blocks 0..15) + fp16 k-pair convert of ALL weights
//          (blocks 16..399, exactly 393216 uints) ----
__global__ __launch_bounds__(1024) void sortconv_kernel(
    const float* __restrict__ W1, const float* __restrict__ b1,
    const float* __restrict__ Wqkv, const float* __restrict__ Wo,
    const float* __restrict__ Wf1, const float* __restrict__ Wf2,
    float* __restrict__ t_sorted, int* __restrict__ idx_sorted,
    unsigned int* __restrict__ wb) {
  __shared__ float ts[HID];
  __shared__ int part[64][17];
  const int tid = threadIdx.x;
  const int bx = blockIdx.x;
  if (bx < 16) {
    {
      const float w = W1[tid];
      ts[tid] = (w != 0.f) ? (-b1[tid] / w) : INFINITY;
    }
    __syncthreads();
    const int hl = tid >> 4;
    const int ck = tid & 15;
    const int h = bx * 64 + hl;
    const float t = ts[h];
    int cnt = 0;
    const int r0 = ck * 64;
#pragma unroll 4
    for (int rr = 0; rr < 64; ++rr) {
      const int r = r0 + rr;
      const float tv = ts[r];
      cnt += ((tv < t) || (tv == t && r < h)) ? 1 : 0;
    }
    part[hl][ck] = cnt;
    __syncthreads();
    if (ck == 0) {
      int rank = 0;
#pragma unroll
      for (int u = 0; u < 16; ++u) rank += part[hl][u];
      t_sorted[rank] = t;
      idx_sorted[rank] = h;
    }
  } else {
    const int p = (bx - 16) * 1024 + tid;
    float a, b;
    if (p < WB_WO) {
      const int kp = p / 768, col = p % 768;
      a = Wqkv[(2 * kp) * 768 + col];
      b = Wqkv[(2 * kp + 1) * 768 + col];
    } else if (p < WB_WF1) {
      const int q = p - WB_WO;
      const int kp = q >> 8, cc = q & 255;
      a = Wo[(2 * kp) * DIMX + cc];
      b = Wo[(2 * kp + 1) * DIMX + cc];
    } else if (p < WB_WF2) {
      const int q = p - WB_WF1;
      const int kp = q >> 10, hh = q & 1023;
      a = Wf1[(2 * kp) * HID + hh];
      b = Wf1[(2 * kp + 1) * HID + hh];
    } else {
      const int q = p - WB_WF2;
      const int kp = q >> 8, cc = q & 255;
      a = Wf2[(2 * kp) * DIMX + cc];
      b = Wf2[(2 * kp + 1) * DIMX + cc];
    }
    wb[p] = pkh_rn(a, b);
  }
}

// ---- K2: qkv GEMM fp16-dot2 (blocks 0..95, 4 rows) + scan (96..351) ----
__global__ __launch_bounds__(1024) void qkvscan_kernel(
    const float* __restrict__ x, const unsigned int* __restrict__ wqkvH,
    const float* __restrict__ bqkv, const float* __restrict__ W1,
    const float* __restrict__ b1, const float* __restrict__ W2,
    const float* __restrict__ b2, const int* __restrict__ idx_sorted,
    float* __restrict__ kk, unsigned int* __restrict__ qvp,
    unsigned int* __restrict__ SCp) {
  __shared__ unsigned int xsH[4][128];  // 2 KB packed half2 k-pairs
  __shared__ float red[4][4][768];      // 48 KB
  __shared__ float sW1[HID];            // scan: 4 KB
  __shared__ float sb1[HID];            // 4 KB
  __shared__ int sidx[HID];             // 4 KB
  __shared__ float bws[16], bwc[16], tws[16], twc[16];
  const int tid = threadIdx.x;
  const int bx = blockIdx.x;
  if (bx < 96) {
    const int r0 = bx * 4;
    const int kc = tid >> 8;   // 4-way k split (32 k-pairs each)
    const int c = tid & 255;
    if (tid < 512) {
      const int rr2 = tid >> 7, c2 = tid & 127;
      const float2 f = ((const float2*)x)[(r0 + rr2) * 128 + c2];
      xsH[rr2][c2] = pkh(f.x, f.y);
    }
    __syncthreads();
    float acc[4][3];
#pragma unroll
    for (int rr = 0; rr < 4; ++rr)
      for (int u = 0; u < 3; ++u) acc[rr][u] = 0.f;
    const int kp0 = kc * 32;
#pragma unroll 4
    for (int i = 0; i < 32; ++i) {
      const int kp = kp0 + i;
      const unsigned int w0 = wqkvH[kp * 768 + c];
      const unsigned int w1 = wqkvH[kp * 768 + 256 + c];
      const unsigned int w2 = wqkvH[kp * 768 + 512 + c];
#pragma unroll
      for (int rr = 0; rr < 4; ++rr) {
        const unsigned int xa = xsH[rr][kp];
        acc[rr][0] = fdot2u(w0, xa, acc[rr][0]);
        acc[rr][1] = fdot2u(w1, xa, acc[rr][1]);
        acc[rr][2] = fdot2u(w2, xa, acc[rr][2]);
      }
    }
#pragma unroll
    for (int rr = 0; rr < 4; ++rr) {
      red[kc][rr][c] = acc[rr][0];
      red[kc][rr][256 + c] = acc[rr][1];
      red[kc][rr][512 + c] = acc[rr][2];
    }
    __syncthreads();
    {
      const int rr = tid >> 8;
      const int row = r0 + rr;
      const float q = red[0][rr][c] + red[1][rr][c] + red[2][rr][c] +
                      red[3][rr][c] + bqkv[c];
      const float kkv = red[0][rr][256 + c] + red[1][rr][256 + c] +
                        red[2][rr][256 + c] + red[3][rr][256 + c] +
                        bqkv[256 + c];
      const float v = red[0][rr][512 + c] + red[1][rr][512 + c] +
                      red[2][rr][512 + c] + red[3][rr][512 + c] +
                      bqkv[512 + c];
      kk[row * DIMX + c] = kkv;
      qvp[row * DIMX + c] = f2b(q * (SCALING * LOG2E)) | (f2b(v) << 16);
    }
  } else {
    // ---- scan: one channel per block ----
    const int c = bx - 96;
    const int lane = tid & 63;
    const int wid = tid >> 6;

    const float w = W1[tid];
    const float b1s = b1[tid];
    sW1[tid] = w;
    sb1[tid] = b1s;
    sidx[tid] = idx_sorted[tid];

    float bs = 0.f, bc = 0.f;
    {
      const float w2v = W2[tid * DIMX + c];
      if (w < 0.f) {
        bs = w * w2v;
        bc = b1s * w2v;
      } else if (w == 0.f && b1s > 0.f) {
        bc = b1s * w2v;
      }
    }
    for (int off = 32; off > 0; off >>= 1) {
      bs += __shfl_down(bs, off);
      bc += __shfl_down(bc, off);
    }
    __syncthreads();

    float vS, vC;
    {
      const int hh = sidx[tid];
      const float w1v = sW1[hh];
      const float sign = (w1v > 0.f) ? 1.f : -1.f;
      const float coefS = (w1v == 0.f) ? 0.f : sign * w1v;
      const float coefC = (w1v == 0.f) ? 0.f : sign * sb1[hh];
      const float w2v = W2[hh * DIMX + c];
      vS = coefS * w2v;
      vC = coefC * w2v;
    }
    for (int off = 1; off < 64; off <<= 1) {
      const float tS_ = __shfl_up(vS, off);
      const float tC_ = __shfl_up(vC, off);
      if (lane >= off) {
        vS += tS_;
        vC += tC_;
      }
    }
    if (lane == 0) {
      bws[wid] = bs;
      bwc[wid] = bc;
    }
    if (lane == 63) {
      tws[wid] = vS;
      twc[wid] = vC;
    }
    __syncthreads();
    float S0 = 0.f, C0 = 0.f, offS = 0.f, offC = 0.f;
#pragma unroll
    for (int u = 0; u < 16; ++u) {
      S0 += bws[u];
      C0 += bwc[u];
      if (u < wid) {
        offS += tws[u];
        offC += twc[u];
      }
    }
    C0 += b2[c];
    SCp[(tid + 1) * DIMX + c] = f2b(S0 + offS + vS) | (f2b(C0 + offC + vC) << 16);
    if (tid == 0) SCp[c] = f2b(S0) | (f2b(C0) << 16);
  }
}

// ------- K3: fused distance-attention, packed bf16 SC/qv, exp2 softmax -----
__global__ __launch_bounds__(1024) void attn_kernel(
    const float* __restrict__ pos, const int* __restrict__ mask,
    const float* __restrict__ kk, const unsigned int* __restrict__ qvp,
    const float* __restrict__ t_sorted, const unsigned int* __restrict__ SCp,
    float* __restrict__ att) {
  __shared__ float tS[HID];
  __shared__ float posB[NN][3];
  __shared__ int maskB[NN];
  __shared__ float dJ[NN];
  __shared__ float decJ[NN];
  __shared__ int segJ[NN];
  __shared__ int pmJ[NN];
  __shared__ float sl[4][DIMX];
  __shared__ float so[4][DIMX];

  const int r = blockIdx.x;
  const int b = r / NN;
  const int i = r % NN;
  const int tid = threadIdx.x;
  const int c = tid & 255;
  const int jq = tid >> 8;

  tS[tid] = t_sorted[tid];
  if (tid < NN) {
    posB[tid][0] = pos[(b * NN + tid) * 3 + 0];
    posB[tid][1] = pos[(b * NN + tid) * 3 + 1];
    posB[tid][2] = pos[(b * NN + tid) * 3 + 2];
    maskB[tid] = mask[b * NN + tid];
  }
  __syncthreads();

  if (tid < NN) {
    const int j = tid;
    const float dx = posB[j][0] - posB[i][0];
    const float dy = posB[j][1] - posB[i][1];
    const float dz = posB[j][2] - posB[i][2];
    const float sq = dx * dx + dy * dy + dz * dz;
    const float d = (sq > 0.f) ? sqrtf(sq) : 0.f;
    dJ[j] = d;
    decJ[j] = __expf(-sq * 0.1f);
    int lo = 0, hi = HID;
    while (lo < hi) {
      const int mid = (lo + hi) >> 1;
      if (tS[mid] <= d) lo = mid + 1;
      else hi = mid;
    }
    segJ[j] = lo;
    pmJ[j] = maskB[i] && maskB[j];
  }
  __syncthreads();

  const float kc_ = kk[(b * NN + i) * DIMX + c];
  float l = 0.f, o = 0.f;
  const int j0 = jq * 48;
#pragma unroll 4
  for (int jj = 0; jj < 48; ++jj) {
    const int j = j0 + jj;
    const int seg = segJ[j];
    const unsigned int scu = SCp[seg * DIMX + c];
    const float de = fmaf(dJ[j], blo(scu), bhi(scu));
    const unsigned int qvu = qvp[(b * NN + j) * DIMX + c];
    const float sval = decJ[j] * blo(qvu) * (kc_ + de);
    const float p = pmJ[j] ? 0.f : exp2f(sval);
    l += p;
    o = fmaf(p, bhi(qvu), o);
  }
  sl[jq][c] = l;
  so[jq][c] = o;
  __syncthreads();
  if (tid < DIMX) {
    const float lt = sl[0][tid] + sl[1][tid] + sl[2][tid] + sl[3][tid];
    const float ot = so[0][tid] + so[1][tid] + so[2][tid] + so[3][tid];
    att[r * DIMX + tid] = ot / lt;
  }
}

// ------- K4: fused tail, 2 rows/block (192 blocks), fp16 k-pair + dot2 -----
__global__ __launch_bounds__(1024) void tail_kernel(
    const float* __restrict__ att, const float* __restrict__ x,
    const unsigned int* __restrict__ woH, const float* __restrict__ bo,
    const float* __restrict__ ln1g, const float* __restrict__ ln1b,
    const uint4* __restrict__ wf1H, const float* __restrict__ bf1,
    const uint4* __restrict__ wf2H, const float* __restrict__ bf2,
    const float* __restrict__ ln2g, const float* __restrict__ ln2b,
    float* __restrict__ out) {
  __shared__ float4 red[16][2][64];       // 32 KB, multi-view across phases
  __shared__ unsigned int attsH[2][128];  // 1 KB packed half2 (k-pairs)
  __shared__ unsigned int x1sH[2][128];   // 1 KB
  __shared__ unsigned int hidsH[2][512];  // 4 KB
  __shared__ float x1tmp[2][DIMX];        // 2 KB
  __shared__ float hidtmp[2][HID];        // 8 KB
  __shared__ float lr1[8], lr2[8];
  const int r0 = blockIdx.x * 2;
  const int tid = threadIdx.x;
  const int rr = tid >> 8;   // 0..3 (rows valid 0..1)
  const int c = tid & 255;

  if (tid < 256) {
    const int rr2 = tid >> 7, c2 = tid & 127;
    const float2 f = ((const float2*)att)[(r0 + rr2) * 128 + c2];
    attsH[rr2][c2] = pkh(f.x, f.y);
  }
  __syncthreads();

  // ---- proj: ks = tid>>8 (4 chunks x 32 kp), c = tid&255 ----
  {
    const int ks = tid >> 8;
    float a0 = 0.f, a1 = 0.f;
#pragma unroll 8
    for (int i = 0; i < 32; ++i) {
      const int kp = ks * 32 + i;
      const unsigned int wu = woH[kp * 256 + c];
      a0 = fdot2u(wu, attsH[0][kp], a0);
      a1 = fdot2u(wu, attsH[1][kp], a1);
    }
    float* redp = (float*)red;
    redp[(ks * 2 + 0) * 256 + c] = a0;
    redp[(ks * 2 + 1) * 256 + c] = a1;
  }
  __syncthreads();
  float t1 = 0.f, x1v = 0.f;
  if (rr < 2) {
    const float* redp = (const float*)red;
    const float pv = redp[(0 * 2 + rr) * 256 + c] + redp[(1 * 2 + rr) * 256 + c] +
                     redp[(2 * 2 + rr) * 256 + c] + redp[(3 * 2 + rr) * 256 + c];
    t1 = pv + x[(r0 + rr) * DIMX + c] + bo[c];
  }
  // ---- LN1 ----
  {
    float s1 = t1, s2 = t1 * t1;
    for (int off = 32; off > 0; off >>= 1) {
      s1 += __shfl_down(s1, off);
      s2 += __shfl_down(s2, off);
    }
    if ((tid & 63) == 0 && tid < 512) { lr1[tid >> 6] = s1; lr2[tid >> 6] = s2; }
  }
  __syncthreads();
  if (rr < 2) {
    const int base = rr * 4;
    const float S1 = lr1[base] + lr1[base + 1] + lr1[base + 2] + lr1[base + 3];
    const float S2 = lr2[base] + lr2[base + 1] + lr2[base + 2] + lr2[base + 3];
    const float mu = S1 * (1.f / DIMX);
    const float var = S2 * (1.f / DIMX) - mu * mu;
    x1v = (t1 - mu) * rsqrtf(var + EPS) * ln1g[c] + ln1b[c];
    x1tmp[rr][c] = x1v;
  }
  __syncthreads();
  if (tid < 256) {
    const int rr2 = tid >> 7, c2 = tid & 127;
    x1sH[rr2][c2] = pkh(x1tmp[rr2][2 * c2], x1tmp[rr2][2 * c2 + 1]);
  }
  __syncthreads();

  // ---- FFN1: ks = tid>>8 (4 chunks x 32 kp), h4 = tid&255 (4 cols) ----
  {
    const int ks = tid >> 8, h4 = tid & 255;
    float4 a0 = {0.f, 0.f, 0.f, 0.f}, a1 = {0.f, 0.f, 0.f, 0.f};
#pragma unroll 4
    for (int i = 0; i < 32; ++i) {
      const int kp = ks * 32 + i;
      const uint4 wv = wf1H[kp * 256 + h4];
      const unsigned int xa = x1sH[0][kp], xb = x1sH[1][kp];
      a0.x = fdot2u(wv.x, xa, a0.x);
      a0.y = fdot2u(wv.y, xa, a0.y);
      a0.z = fdot2u(wv.z, xa, a0.z);
      a0.w = fdot2u(wv.w, xa, a0.w);
      a1.x = fdot2u(wv.x, xb, a1.x);
      a1.y = fdot2u(wv.y, xb, a1.y);
      a1.z = fdot2u(wv.z, xb, a1.z);
      a1.w = fdot2u(wv.w, xb, a1.w);
    }
    float4* redf4 = (float4*)red;
    redf4[(ks * 2 + 0) * 256 + h4] = a0;
    redf4[(ks * 2 + 1) * 256 + h4] = a1;
  }
  __syncthreads();
  {
    const float* redf = (const float*)red;
    const float bf = bf1[tid];
    const float v0 = redf[0 * 1024 + tid] + redf[2 * 1024 + tid] +
                     redf[4 * 1024 + tid] + redf[6 * 1024 + tid];
    const float v1 = redf[1 * 1024 + tid] + redf[3 * 1024 + tid] +
                     redf[5 * 1024 + tid] + redf[7 * 1024 + tid];
    hidtmp[0][tid] = fmaxf(v0 + bf, 0.f);
    hidtmp[1][tid] = fmaxf(v1 + bf, 0.f);
  }
  __syncthreads();
  {
    const int rr2 = tid >> 9, c2 = tid & 511;
    hidsH[rr2][c2] = pkh(hidtmp[rr2][2 * c2], hidtmp[rr2][2 * c2 + 1]);
  }
  __syncthreads();

  // ---- FFN2: ks = tid>>6 (16 chunks x 32 kp of 512), c4 = tid&63 ----
  {
    const int ks = tid >> 6, c4 = tid & 63;
    float4 a0 = {0.f, 0.f, 0.f, 0.f}, a1 = {0.f, 0.f, 0.f, 0.f};
#pragma unroll 4
    for (int i = 0; i < 32; ++i) {
      const int kp = ks * 32 + i;
      const uint4 wv = wf2H[kp * 64 + c4];
      const unsigned int ha = hidsH[0][kp], hb = hidsH[1][kp];
      a0.x = fdot2u(wv.x, ha, a0.x);
      a0.y = fdot2u(wv.y, ha, a0.y);
      a0.z = fdot2u(wv.z, ha, a0.z);
      a0.w = fdot2u(wv.w, ha, a0.w);
      a1.x = fdot2u(wv.x, hb, a1.x);
      a1.y = fdot2u(wv.y, hb, a1.y);
      a1.z = fdot2u(wv.z, hb, a1.z);
      a1.w = fdot2u(wv.w, hb, a1.w);
    }
    red[ks][0][c4] = a0;
    red[ks][1][c4] = a1;
  }
  __syncthreads();
  float t2 = 0.f;
  if (rr < 2) {
    const int c4 = c >> 2, cm = c & 3;
    float pv = 0.f;
#pragma unroll
    for (int u = 0; u < 16; ++u) pv += ((const float*)&red[u][rr][c4])[cm];
    t2 = pv + x1v + bf2[c];
  }
  // ---- LN2 ----
  {
    float s1 = t2, s2 = t2 * t2;
    for (int off = 32; off > 0; off >>= 1) {
      s1 += __shfl_down(s1, off);
      s2 += __shfl_down(s2, off);
    }
    if ((tid & 63) == 0 && tid < 512) { lr1[tid >> 6] = s1; lr2[tid >> 6] = s2; }
  }
  __syncthreads();
  if (rr < 2) {
    const int base = rr * 4;
    const float S1 = lr1[base] + lr1[base + 1] + lr1[base + 2] + lr1[base + 3];
    const float S2 = lr2[base] + lr2[base + 1] + lr2[base + 2] + lr2[base + 3];
    const float mu = S1 * (1.f / DIMX);
    const float var = S2 * (1.f / DIMX) - mu * mu;
    out[(r0 + rr) * DIMX + c] = (t2 - mu) * rsqrtf(var + EPS) * ln2g[c] + ln2b[c];
  }
}

extern "C" void kernel_launch(void* const* d_in, const int* in_sizes, int n_in,
                              void* d_out, int out_size, void* d_ws,
                              size_t ws_size, hipStream_t stream) {
  const float* x = (const float*)d_in[0];
  const float* pos = (const float*)d_in[1];
  const int* mask = (const int*)d_in[2];
  const float* Wqkv = (const float*)d_in[3];
  const float* bqkv = (const float*)d_in[4];
  const float* W1 = (const float*)d_in[5];
  const float* b1 = (const float*)d_in[6];
  const float* W2 = (const float*)d_in[7];
  const float* b2 = (const float*)d_in[8];
  const float* Wo = (const float*)d_in[9];
  const float* bo = (const float*)d_in[10];
  const float* ln1g = (const float*)d_in[11];
  const float* ln1b = (const float*)d_in[12];
  const float* Wf1 = (const float*)d_in[13];
  const float* bf1 = (const float*)d_in[14];
  const float* Wf2 = (const float*)d_in[15];
  const float* bf2 = (const float*)d_in[16];
  const float* ln2g = (const float*)d_in[17];
  const float* ln2b = (const float*)d_in[18];

  float* ws = (float*)d_ws;
  float* kk = ws + OFF_KK;
  unsigned int* qvp = (unsigned int*)(ws + OFF_QVP);
  float* t_sorted = ws + OFF_TSORT;
  int* idx_sorted = (int*)(ws + OFF_IDX);
  unsigned int* SCp = (unsigned int*)(ws + OFF_SCP);
  float* att = ws + OFF_ATT;
  unsigned int* wb = (unsigned int*)(ws + OFF_WB);
  float* outp = (float*)d_out;

  hipLaunchKernelGGL(sortconv_kernel, dim3(400), dim3(1024), 0, stream, W1,
                     b1, Wqkv, Wo, Wf1, Wf2, t_sorted, idx_sorted, wb);
  hipLaunchKernelGGL(qkvscan_kernel, dim3(352), dim3(1024), 0, stream, x,
                     wb + WB_QKVH, bqkv, W1, b1, W2, b2, idx_sorted, kk, qvp,
                     SCp);
  hipLaunchKernelGGL(attn_kernel, dim3(NROWS), dim3(1024), 0, stream, pos,
                     mask, kk, qvp, t_sorted, SCp, att);
  hipLaunchKernelGGL(tail_kernel, dim3(NROWS / 2), dim3(1024), 0, stream, att,
                     x, wb + WB_WO, bo, ln1g, ln1b,
                     (const uint4*)(wb + WB_WF1), bf1,
                     (const uint4*)(wb + WB_WF2), bf2, ln2g, ln2b, outp);
}

// Round 15
// 57.126 us; speedup vs baseline: 1.0836x; 1.0836x over previous
//
#include <hip/hip_runtime.h>
#include <math.h>

#define NB 2
#define NN 192
#define DIMX 256
#define HID 1024
#define NROWS (NB * NN)            // 384
#define SCALING 0.17677669529663687f  // 1/sqrt(32)
#define LOG2E 1.4426950408889634f
#define EPS 1e-5f

// workspace layout (float/uint offsets)
#define OFF_KK    0                               // fp32 k-part, NROWS*256
#define OFF_QVP   (OFF_KK + NROWS * DIMX)         // packed (q*s*log2e, v) bf16
#define OFF_TSORT (OFF_QVP + NROWS * DIMX)        // 1024
#define OFF_IDX   (OFF_TSORT + HID)               // 1024 ints
#define OFF_SCP   (OFF_IDX + HID)                 // packed (S,C) uints (HID+1)*256
#define OFF_ATT   (OFF_SCP + (HID + 1) * DIMX)
#define OFF_WB    (OFF_ATT + NROWS * DIMX)        // packed fp16 k-pair weights
// fp16 weight regions in uints (2 k's per uint, per column):
#define WB_WO  0        // 32768  : [kp<128][c<256]
#define WB_WF1 32768    // 131072 : [kp<128][h<1024]
#define WB_WF2 163840   // 131072 : [kp<512][c<256]
#define WB_TOT 294912

typedef __fp16 half2_t __attribute__((ext_vector_type(2)));

__device__ inline unsigned int f2b(float f) {
  const unsigned int u = __float_as_uint(f);
  return (u + 0x7fffu + ((u >> 16) & 1u)) >> 16;
}
__device__ inline float blo(unsigned int u) {
  return __uint_as_float(u << 16);
}
__device__ inline float bhi(unsigned int u) {
  return __uint_as_float(u & 0xffff0000u);
}
// pack two floats to half2 (rtz, fast path for activations)
__device__ inline unsigned int pkh(float a, float b) {
  union { half2_t h; unsigned int u; } x;
  x.h = __builtin_amdgcn_cvt_pkrtz(a, b);
  return x.u;
}
// round-to-nearest pack (weights, one-time)
__device__ inline unsigned int pkh_rn(float a, float b) {
  union { half2_t h; unsigned int u; } x;
  x.h = half2_t{(__fp16)a, (__fp16)b};
  return x.u;
}
// d = dot2(w, a) + c  (v_dot2_f32_f16)
__device__ inline float fdot2u(unsigned int wu, unsigned int au, float c) {
  union { unsigned int u; half2_t h; } w, a;
  w.u = wu;
  a.u = au;
  return __builtin_amdgcn_fdot2(a.h, w.h, c, false);
}

// ---- K1: qkv GEMM (blocks 0..95, 4 rows) + sortrank (96..111) +
//          weight fp16 k-pair convert (112..399) ----
__global__ __launch_bounds__(1024) void prep_kernel(
    const float* __restrict__ x, const float* __restrict__ Wqkv,
    const float* __restrict__ bqkv, const float* __restrict__ W1,
    const float* __restrict__ b1, const float* __restrict__ Wo,
    const float* __restrict__ Wf1, const float* __restrict__ Wf2,
    float* __restrict__ kk, unsigned int* __restrict__ qvp,
    float* __restrict__ t_sorted, int* __restrict__ idx_sorted,
    unsigned int* __restrict__ wb) {
  __shared__ float xs[4][DIMX];       // 4 KB
  __shared__ float red[4][4][768];    // 48 KB
  __shared__ float ts[HID];           // 4 KB
  __shared__ int part[64][17];        // 4.3 KB
  const int tid = threadIdx.x;
  const int bx = blockIdx.x;
  if (bx < 96) {
    const int r0 = bx * 4;
    const int kc = tid >> 8;       // 4-way k split
    const int c = tid & 255;
    xs[tid >> 8][tid & 255] = x[(r0 + (tid >> 8)) * DIMX + (tid & 255)];
    __syncthreads();
    float acc[4][3];
#pragma unroll
    for (int rr = 0; rr < 4; ++rr)
      for (int u = 0; u < 3; ++u) acc[rr][u] = 0.f;
    const int k0 = kc * 64;
#pragma unroll 4
    for (int i = 0; i < 64; ++i) {
      const int k = k0 + i;
      const float w0 = Wqkv[k * 768 + c];
      const float w1 = Wqkv[k * 768 + 256 + c];
      const float w2 = Wqkv[k * 768 + 512 + c];
#pragma unroll
      for (int rr = 0; rr < 4; ++rr) {
        const float xv = xs[rr][k];
        acc[rr][0] += xv * w0;
        acc[rr][1] += xv * w1;
        acc[rr][2] += xv * w2;
      }
    }
#pragma unroll
    for (int rr = 0; rr < 4; ++rr) {
      red[kc][rr][c] = acc[rr][0];
      red[kc][rr][256 + c] = acc[rr][1];
      red[kc][rr][512 + c] = acc[rr][2];
    }
    __syncthreads();
    {
      const int rr = tid >> 8;
      const int row = r0 + rr;
      const float q = red[0][rr][c] + red[1][rr][c] + red[2][rr][c] +
                      red[3][rr][c] + bqkv[c];
      const float kkv = red[0][rr][256 + c] + red[1][rr][256 + c] +
                        red[2][rr][256 + c] + red[3][rr][256 + c] +
                        bqkv[256 + c];
      const float v = red[0][rr][512 + c] + red[1][rr][512 + c] +
                      red[2][rr][512 + c] + red[3][rr][512 + c] +
                      bqkv[512 + c];
      kk[row * DIMX + c] = kkv;
      qvp[row * DIMX + c] = f2b(q * (SCALING * LOG2E)) | (f2b(v) << 16);
    }
  } else if (bx < 112) {
    const int bk = bx - 96;
    {
      const float w = W1[tid];
      ts[tid] = (w != 0.f) ? (-b1[tid] / w) : INFINITY;
    }
    __syncthreads();
    const int hl = tid >> 4;
    const int ck = tid & 15;
    const int h = bk * 64 + hl;
    const float t = ts[h];
    int cnt = 0;
    const int r0 = ck * 64;
#pragma unroll 4
    for (int rr = 0; rr < 64; ++rr) {
      const int r = r0 + rr;
      const float tv = ts[r];
      cnt += ((tv < t) || (tv == t && r < h)) ? 1 : 0;
    }
    part[hl][ck] = cnt;
    __syncthreads();
    if (ck == 0) {
      int rank = 0;
#pragma unroll
      for (int u = 0; u < 16; ++u) rank += part[hl][u];
      t_sorted[rank] = t;
      idx_sorted[rank] = h;
    }
  } else {
    const int p = (bx - 112) * 1024 + tid;
    if (p < WB_TOT) {
      float a, b;
      if (p < WB_WF1) {
        const int kp = p >> 8, cc = p & 255;
        a = Wo[(2 * kp) * DIMX + cc];
        b = Wo[(2 * kp + 1) * DIMX + cc];
      } else if (p < WB_WF2) {
        const int q = p - WB_WF1;
        const int kp = q >> 10, hh = q & 1023;
        a = Wf1[(2 * kp) * HID + hh];
        b = Wf1[(2 * kp + 1) * HID + hh];
      } else {
        const int q = p - WB_WF2;
        const int kp = q >> 8, cc = q & 255;
        a = Wf2[(2 * kp) * DIMX + cc];
        b = Wf2[(2 * kp + 1) * DIMX + cc];
      }
      wb[p] = pkh_rn(a, b);
    }
  }
}

// ------- K2: baseline + deltas + wave-shuffle inclusive scan -> SC packed --
__global__ __launch_bounds__(1024) void scan_kernel(
    const float* __restrict__ W1, const float* __restrict__ b1,
    const float* __restrict__ W2, const float* __restrict__ b2,
    const int* __restrict__ idx_sorted, unsigned int* __restrict__ SCp) {
  const int c = blockIdx.x;
  const int tid = threadIdx.x;
  const int lane = tid & 63;
  const int wid = tid >> 6;
  __shared__ float sW1[HID];
  __shared__ float sb1[HID];
  __shared__ int sidx[HID];
  __shared__ float bws[16], bwc[16], tws[16], twc[16];

  const float w = W1[tid];
  const float b1s = b1[tid];
  sW1[tid] = w;
  sb1[tid] = b1s;
  sidx[tid] = idx_sorted[tid];

  float bs = 0.f, bc = 0.f;
  {
    const float w2v = W2[tid * DIMX + c];
    if (w < 0.f) {
      bs = w * w2v;
      bc = b1s * w2v;
    } else if (w == 0.f && b1s > 0.f) {
      bc = b1s * w2v;
    }
  }
  for (int off = 32; off > 0; off >>= 1) {
    bs += __shfl_down(bs, off);
    bc += __shfl_down(bc, off);
  }
  __syncthreads();

  float vS, vC;
  {
    const int hh = sidx[tid];
    const float w1v = sW1[hh];
    const float sign = (w1v > 0.f) ? 1.f : -1.f;
    const float coefS = (w1v == 0.f) ? 0.f : sign * w1v;
    const float coefC = (w1v == 0.f) ? 0.f : sign * sb1[hh];
    const float w2v = W2[hh * DIMX + c];
    vS = coefS * w2v;
    vC = coefC * w2v;
  }
  for (int off = 1; off < 64; off <<= 1) {
    const float tS_ = __shfl_up(vS, off);
    const float tC_ = __shfl_up(vC, off);
    if (lane >= off) {
      vS += tS_;
      vC += tC_;
    }
  }
  if (lane == 0) {
    bws[wid] = bs;
    bwc[wid] = bc;
  }
  if (lane == 63) {
    tws[wid] = vS;
    twc[wid] = vC;
  }
  __syncthreads();
  float S0 = 0.f, C0 = 0.f, offS = 0.f, offC = 0.f;
#pragma unroll
  for (int u = 0; u < 16; ++u) {
    S0 += bws[u];
    C0 += bwc[u];
    if (u < wid) {
      offS += tws[u];
      offC += twc[u];
    }
  }
  C0 += b2[c];
  SCp[(tid + 1) * DIMX + c] = f2b(S0 + offS + vS) | (f2b(C0 + offC + vC) << 16);
  if (tid == 0) SCp[c] = f2b(S0) | (f2b(C0) << 16);
}

// ------- K3: fused distance-attention, packed bf16 SC/qv, exp2 softmax -----
__global__ __launch_bounds__(1024) void attn_kernel(
    const float* __restrict__ pos, const int* __restrict__ mask,
    const float* __restrict__ kk, const unsigned int* __restrict__ qvp,
    const float* __restrict__ t_sorted, const unsigned int* __restrict__ SCp,
    float* __restrict__ att) {
  __shared__ float tS[HID];
  __shared__ float posB[NN][3];
  __shared__ int maskB[NN];
  __shared__ float dJ[NN];
  __shared__ float decJ[NN];
  __shared__ int segJ[NN];
  __shared__ int pmJ[NN];
  __shared__ float sl[4][DIMX];
  __shared__ float so[4][DIMX];

  const int r = blockIdx.x;
  const int b = r / NN;
  const int i = r % NN;
  const int tid = threadIdx.x;
  const int c = tid & 255;
  const int jq = tid >> 8;

  tS[tid] = t_sorted[tid];
  if (tid < NN) {
    posB[tid][0] = pos[(b * NN + tid) * 3 + 0];
    posB[tid][1] = pos[(b * NN + tid) * 3 + 1];
    posB[tid][2] = pos[(b * NN + tid) * 3 + 2];
    maskB[tid] = mask[b * NN + tid];
  }
  __syncthreads();

  if (tid < NN) {
    const int j = tid;
    const float dx = posB[j][0] - posB[i][0];
    const float dy = posB[j][1] - posB[i][1];
    const float dz = posB[j][2] - posB[i][2];
    const float sq = dx * dx + dy * dy + dz * dz;
    const float d = (sq > 0.f) ? sqrtf(sq) : 0.f;
    dJ[j] = d;
    decJ[j] = __expf(-sq * 0.1f);
    int lo = 0, hi = HID;
    while (lo < hi) {
      const int mid = (lo + hi) >> 1;
      if (tS[mid] <= d) lo = mid + 1;
      else hi = mid;
    }
    segJ[j] = lo;
    pmJ[j] = maskB[i] && maskB[j];
  }
  __syncthreads();

  const float kc_ = kk[(b * NN + i) * DIMX + c];
  float l = 0.f, o = 0.f;
  const int j0 = jq * 48;
#pragma unroll 4
  for (int jj = 0; jj < 48; ++jj) {
    const int j = j0 + jj;
    const int seg = segJ[j];
    const unsigned int scu = SCp[seg * DIMX + c];
    const float de = fmaf(dJ[j], blo(scu), bhi(scu));
    const unsigned int qvu = qvp[(b * NN + j) * DIMX + c];
    const float sval = decJ[j] * blo(qvu) * (kc_ + de);
    const float p = pmJ[j] ? 0.f : exp2f(sval);
    l += p;
    o = fmaf(p, bhi(qvu), o);
  }
  sl[jq][c] = l;
  so[jq][c] = o;
  __syncthreads();
  if (tid < DIMX) {
    const float lt = sl[0][tid] + sl[1][tid] + sl[2][tid] + sl[3][tid];
    const float ot = so[0][tid] + so[1][tid] + so[2][tid] + so[3][tid];
    att[r * DIMX + tid] = ot / lt;
  }
}

// ------- K4: fused tail, 2 rows/block (192 blocks), fp16 k-pair + dot2 -----
__global__ __launch_bounds__(1024) void tail_kernel(
    const float* __restrict__ att, const float* __restrict__ x,
    const unsigned int* __restrict__ woH, const float* __restrict__ bo,
    const float* __restrict__ ln1g, const float* __restrict__ ln1b,
    const uint4* __restrict__ wf1H, const float* __restrict__ bf1,
    const uint4* __restrict__ wf2H, const float* __restrict__ bf2,
    const float* __restrict__ ln2g, const float* __restrict__ ln2b,
    float* __restrict__ out) {
  __shared__ float4 red[16][2][64];       // 32 KB, multi-view across phases
  __shared__ unsigned int attsH[2][128];  // 1 KB packed half2 (k-pairs)
  __shared__ unsigned int x1sH[2][128];   // 1 KB
  __shared__ unsigned int hidsH[2][512];  // 4 KB
  __shared__ float x1tmp[2][DIMX];        // 2 KB
  __shared__ float hidtmp[2][HID];        // 8 KB
  __shared__ float lr1[8], lr2[8];
  const int r0 = blockIdx.x * 2;
  const int tid = threadIdx.x;
  const int rr = tid >> 8;   // 0..3 (rows valid 0..1)
  const int c = tid & 255;

  if (tid < 256) {
    const int rr2 = tid >> 7, c2 = tid & 127;
    const float2 f = ((const float2*)att)[(r0 + rr2) * 128 + c2];
    attsH[rr2][c2] = pkh(f.x, f.y);
  }
  __syncthreads();

  // ---- proj: ks = tid>>8 (4 chunks x 32 kp), c = tid&255 ----
  {
    const int ks = tid >> 8;
    float a0 = 0.f, a1 = 0.f;
#pragma unroll 8
    for (int i = 0; i < 32; ++i) {
      const int kp = ks * 32 + i;
      const unsigned int wu = woH[kp * 256 + c];
      a0 = fdot2u(wu, attsH[0][kp], a0);
      a1 = fdot2u(wu, attsH[1][kp], a1);
    }
    float* redp = (float*)red;
    redp[(ks * 2 + 0) * 256 + c] = a0;
    redp[(ks * 2 + 1) * 256 + c] = a1;
  }
  __syncthreads();
  float t1 = 0.f, x1v = 0.f;
  if (rr < 2) {
    const float* redp = (const float*)red;
    const float pv = redp[(0 * 2 + rr) * 256 + c] + redp[(1 * 2 + rr) * 256 + c] +
                     redp[(2 * 2 + rr) * 256 + c] + redp[(3 * 2 + rr) * 256 + c];
    t1 = pv + x[(r0 + rr) * DIMX + c] + bo[c];
  }
  // ---- LN1 ----
  {
    float s1 = t1, s2 = t1 * t1;
    for (int off = 32; off > 0; off >>= 1) {
      s1 += __shfl_down(s1, off);
      s2 += __shfl_down(s2, off);
    }
    if ((tid & 63) == 0 && tid < 512) { lr1[tid >> 6] = s1; lr2[tid >> 6] = s2; }
  }
  __syncthreads();
  if (rr < 2) {
    const int base = rr * 4;
    const float S1 = lr1[base] + lr1[base + 1] + lr1[base + 2] + lr1[base + 3];
    const float S2 = lr2[base] + lr2[base + 1] + lr2[base + 2] + lr2[base + 3];
    const float mu = S1 * (1.f / DIMX);
    const float var = S2 * (1.f / DIMX) - mu * mu;
    x1v = (t1 - mu) * rsqrtf(var + EPS) * ln1g[c] + ln1b[c];
    x1tmp[rr][c] = x1v;
  }
  __syncthreads();
  if (tid < 256) {
    const int rr2 = tid >> 7, c2 = tid & 127;
    x1sH[rr2][c2] = pkh(x1tmp[rr2][2 * c2], x1tmp[rr2][2 * c2 + 1]);
  }
  __syncthreads();

  // ---- FFN1: ks = tid>>8 (4 chunks x 32 kp), h4 = tid&255 (4 cols) ----
  {
    const int ks = tid >> 8, h4 = tid & 255;
    float4 a0 = {0.f, 0.f, 0.f, 0.f}, a1 = {0.f, 0.f, 0.f, 0.f};
#pragma unroll 4
    for (int i = 0; i < 32; ++i) {
      const int kp = ks * 32 + i;
      const uint4 wv = wf1H[kp * 256 + h4];
      const unsigned int xa = x1sH[0][kp], xb = x1sH[1][kp];
      a0.x = fdot2u(wv.x, xa, a0.x);
      a0.y = fdot2u(wv.y, xa, a0.y);
      a0.z = fdot2u(wv.z, xa, a0.z);
      a0.w = fdot2u(wv.w, xa, a0.w);
      a1.x = fdot2u(wv.x, xb, a1.x);
      a1.y = fdot2u(wv.y, xb, a1.y);
      a1.z = fdot2u(wv.z, xb, a1.z);
      a1.w = fdot2u(wv.w, xb, a1.w);
    }
    float4* redf4 = (float4*)red;
    redf4[(ks * 2 + 0) * 256 + h4] = a0;
    redf4[(ks * 2 + 1) * 256 + h4] = a1;
  }
  __syncthreads();
  {
    const float* redf = (const float*)red;
    const float bf = bf1[tid];
    const float v0 = redf[0 * 1024 + tid] + redf[2 * 1024 + tid] +
                     redf[4 * 1024 + tid] + redf[6 * 1024 + tid];
    const float v1 = redf[1 * 1024 + tid] + redf[3 * 1024 + tid] +
                     redf[5 * 1024 + tid] + redf[7 * 1024 + tid];
    hidtmp[0][tid] = fmaxf(v0 + bf, 0.f);
    hidtmp[1][tid] = fmaxf(v1 + bf, 0.f);
  }
  __syncthreads();
  {
    const int rr2 = tid >> 9, c2 = tid & 511;
    hidsH[rr2][c2] = pkh(hidtmp[rr2][2 * c2], hidtmp[rr2][2 * c2 + 1]);
  }
  __syncthreads();

  // ---- FFN2: ks = tid>>6 (16 chunks x 32 kp of 512), c4 = tid&63 ----
  {
    const int ks = tid >> 6, c4 = tid & 63;
    float4 a0 = {0.f, 0.f, 0.f, 0.f}, a1 = {0.f, 0.f, 0.f, 0.f};
#pragma unroll 4
    for (int i = 0; i < 32; ++i) {
      const int kp = ks * 32 + i;
      const uint4 wv = wf2H[kp * 64 + c4];
      const unsigned int ha = hidsH[0][kp], hb = hidsH[1][kp];
      a0.x = fdot2u(wv.x, ha, a0.x);
      a0.y = fdot2u(wv.y, ha, a0.y);
      a0.z = fdot2u(wv.z, ha, a0.z);
      a0.w = fdot2u(wv.w, ha, a0.w);
      a1.x = fdot2u(wv.x, hb, a1.x);
      a1.y = fdot2u(wv.y, hb, a1.y);
      a1.z = fdot2u(wv.z, hb, a1.z);
      a1.w = fdot2u(wv.w, hb, a1.w);
    }
    red[ks][0][c4] = a0;
    red[ks][1][c4] = a1;
  }
  __syncthreads();
  float t2 = 0.f;
  if (rr < 2) {
    const int c4 = c >> 2, cm = c & 3;
    float pv = 0.f;
#pragma unroll
    for (int u = 0; u < 16; ++u) pv += ((const float*)&red[u][rr][c4])[cm];
    t2 = pv + x1v + bf2[c];
  }
  // ---- LN2 ----
  {
    float s1 = t2, s2 = t2 * t2;
    for (int off = 32; off > 0; off >>= 1) {
      s1 += __shfl_down(s1, off);
      s2 += __shfl_down(s2, off);
    }
    if ((tid & 63) == 0 && tid < 512) { lr1[tid >> 6] = s1; lr2[tid >> 6] = s2; }
  }
  __syncthreads();
  if (rr < 2) {
    const int base = rr * 4;
    const float S1 = lr1[base] + lr1[base + 1] + lr1[base + 2] + lr1[base + 3];
    const float S2 = lr2[base] + lr2[base + 1] + lr2[base + 2] + lr2[base + 3];
    const float mu = S1 * (1.f / DIMX);
    const float var = S2 * (1.f / DIMX) - mu * mu;
    out[(r0 + rr) * DIMX + c] = (t2 - mu) * rsqrtf(var + EPS) * ln2g[c] + ln2b[c];
  }
}

extern "C" void kernel_launch(void* const* d_in, const int* in_sizes, int n_in,
                              void* d_out, int out_size, void* d_ws,
                              size_t ws_size, hipStream_t stream) {
  const float* x = (const float*)d_in[0];
  const float* pos = (const float*)d_in[1];
  const int* mask = (const int*)d_in[2];
  const float* Wqkv = (const float*)d_in[3];
  const float* bqkv = (const float*)d_in[4];
  const float* W1 = (const float*)d_in[5];
  const float* b1 = (const float*)d_in[6];
  const float* W2 = (const float*)d_in[7];
  const float* b2 = (const float*)d_in[8];
  const float* Wo = (const float*)d_in[9];
  const float* bo = (const float*)d_in[10];
  const float* ln1g = (const float*)d_in[11];
  const float* ln1b = (const float*)d_in[12];
  const float* Wf1 = (const float*)d_in[13];
  const float* bf1 = (const float*)d_in[14];
  const float* Wf2 = (const float*)d_in[15];
  const float* bf2 = (const float*)d_in[16];
  const float* ln2g = (const float*)d_in[17];
  const float* ln2b = (const float*)d_in[18];

  float* ws = (float*)d_ws;
  float* kk = ws + OFF_KK;
  unsigned int* qvp = (unsigned int*)(ws + OFF_QVP);
  float* t_sorted = ws + OFF_TSORT;
  int* idx_sorted = (int*)(ws + OFF_IDX);
  unsigned int* SCp = (unsigned int*)(ws + OFF_SCP);
  float* att = ws + OFF_ATT;
  unsigned int* wb = (unsigned int*)(ws + OFF_WB);
  float* outp = (float*)d_out;

  hipLaunchKernelGGL(prep_kernel, dim3(400), dim3(1024), 0, stream, x, Wqkv,
                     bqkv, W1, b1, Wo, Wf1, Wf2, kk, qvp, t_sorted, idx_sorted,
                     wb);
  hipLaunchKernelGGL(scan_kernel, dim3(DIMX), dim3(1024), 0, stream, W1, b1,
                     W2, b2, idx_sorted, SCp);
  hipLaunchKernelGGL(attn_kernel, dim3(NROWS), dim3(1024), 0, stream, pos,
                     mask, kk, qvp, t_sorted, SCp, att);
  hipLaunchKernelGGL(tail_kernel, dim3(NROWS / 2), dim3(1024), 0, stream, att,
                     x, wb + WB_WO, bo, ln1g, ln1b,
                     (const uint4*)(wb + WB_WF1), bf1,
                     (const uint4*)(wb + WB_WF2), bf2, ln2g, ln2b, outp);
}